// Round 3
// baseline (41.410 us; speedup 1.0000x reference)
//
#include <hip/hip_runtime.h>

// MTRNN single step. Live computation after DCE (reference returns only y):
//   io_new = tanh([x|io|cf] @ (0.5*[Wi2io | Wio2io+I | Wcf2io])^T + 0.5*bsum)
//   y      = tanh(io_new @ Wio2o^T + bio2o)
// (0.5*io_state folded into the weight matrix via +I on the io2io block.)
// cf_new / cs_new are dead code. bf16 MFMA, f32 accumulate.

typedef float f32x4 __attribute__((ext_vector_type(4)));
typedef __bf16 bf16x8 __attribute__((ext_vector_type(8)));
typedef unsigned short u16x8 __attribute__((ext_vector_type(8)));
typedef unsigned short u16x4 __attribute__((ext_vector_type(4)));

__device__ __forceinline__ unsigned short f2bf(float f) {
    unsigned u = __builtin_bit_cast(unsigned, f);
    u += 0x7FFFu + ((u >> 16) & 1u);
    return (unsigned short)(u >> 16);
}

// XOR swizzle for [rows][64] bf16 tiles (row stride 128 B): kills the
// 128B-stride bank conflict on ds_read_b128 (Guideline 4, T2).
__device__ __forceinline__ int swz(int row, int kbyte) {
    return ((row << 7) + kbyte) ^ ((row & 7) << 4);
}

// ---------------------------------------------------------------------------
// Kernel 0: pack live weights to bf16.
//   wcat[512][1152] = 0.5*[Wi2io | Wio2io + I | Wcf2io]   (leaky-int folded)
//   w2  [128][512]  = Wio2o
// ---------------------------------------------------------------------------
__global__ __launch_bounds__(256) void k_convert(
    const float* __restrict__ Wi2io, const float* __restrict__ Wio2io,
    const float* __restrict__ Wcf2io, const float* __restrict__ Wio2o,
    unsigned short* __restrict__ wcat, unsigned short* __restrict__ w2)
{
    int idx = blockIdx.x * 256 + threadIdx.x;
    if (idx < 147456) {              // 512*1152/4 quads
        int n = idx / 288;
        int k = (idx - n * 288) * 4;
        const float* s;
        if (k < 128)      s = Wi2io  + n * 128 + k;
        else if (k < 640) s = Wio2io + n * 512 + (k - 128);
        else              s = Wcf2io + n * 512 + (k - 640);
        f32x4 v = *(const f32x4*)s;
        u16x4 h;
        #pragma unroll
        for (int t = 0; t < 4; ++t) {
            float f = 0.5f * v[t];
            int kk = k + t;
            if (kk >= 128 && kk < 640 && (kk - 128) == n) f += 0.5f;  // +0.5*I
            h[t] = f2bf(f);
        }
        *(u16x4*)(wcat + n * 1152 + k) = h;
    } else if (idx < 163840) {       // + 128*512/4 quads
        int q = idx - 147456;
        int n = q >> 7;
        int k = (q & 127) * 4;
        f32x4 v = *(const f32x4*)(Wio2o + n * 512 + k);
        u16x4 h; h[0]=f2bf(v[0]); h[1]=f2bf(v[1]); h[2]=f2bf(v[2]); h[3]=f2bf(v[3]);
        *(u16x4*)(w2 + n * 512 + k) = h;
    }
}

// ---------------------------------------------------------------------------
// Kernel 1: ionew = tanh(Acat @ wcat^T + 0.5*bsum), bf16 out.
// M=8192 N=512 K=1152. Tile 64x64, BK=64, 256 thr (4 waves 2x2, wave 32x32).
// Grid 1024 -> 4 blocks/CU (LDS 32KB dbuf). 2-deep issue pipeline: loads for
// kt+2 are in flight while kt computes and kt+1 is written to LDS.
// XCD swizzle: all 8 col-blocks of a 64-row A panel co-resident on one XCD.
// ---------------------------------------------------------------------------
__global__ __launch_bounds__(256, 4) void k_gemm1(
    const float* __restrict__ x, const float* __restrict__ io,
    const float* __restrict__ cf,
    const unsigned short* __restrict__ wcat,
    const float* __restrict__ b1, const float* __restrict__ b2,
    const float* __restrict__ b3,
    unsigned short* __restrict__ ionew)
{
    // per buffer: A 64x64 bf16 (8 KB) @0, B 64x64 bf16 (8 KB) @8192
    __shared__ __align__(16) char lds[2][16384];

    const int tid = threadIdx.x;
    const int b   = blockIdx.x;
    // XCD x (== b&7, dispatch round-robin) owns row panels [16x, 16x+16).
    const int xcd   = b & 7;
    const int idx   = b >> 3;                 // 0..127
    const int panel = (xcd << 4) | (idx & 15); // 0..127
    const int colb  = idx >> 4;                // 0..7
    const int m0 = panel << 6;
    const int n0 = colb << 6;

    const int lane = tid & 63;
    const int wid  = tid >> 6;
    const int wm   = (wid >> 1) << 5;     // 0 / 32
    const int wn   = (wid & 1) << 5;      // 0 / 32
    const int lrow = lane & 15;
    const int lk2  = (lane >> 4) << 4;    // k byte offset within 128B row

    f32x4 ra0[4], ra1[4];
    u16x8 rb0[2], rb1[2];
    f32x4 acc[2][2];
    f32x4 z = {0.f, 0.f, 0.f, 0.f};
    #pragma unroll
    for (int i = 0; i < 2; ++i)
        #pragma unroll
        for (int j = 0; j < 2; ++j) acc[i][j] = z;

#define ISSUE1(RA, RB, KT) do {                                                \
        int K_ = (KT);                                                         \
        const float* sp; int st, c0;                                           \
        if (K_ < 2)       { sp = x;  st = 128; c0 = K_ << 6; }                 \
        else if (K_ < 10) { sp = io; st = 512; c0 = (K_ - 2) << 6; }           \
        else              { sp = cf; st = 512; c0 = (K_ - 10) << 6; }          \
        _Pragma("unroll")                                                      \
        for (int j = 0; j < 4; ++j) {                                          \
            int q = tid + 256 * j;                                             \
            RA[j] = *(const f32x4*)(sp + (size_t)(m0 + (q >> 4)) * st          \
                                       + c0 + ((q & 15) << 2));                \
        }                                                                      \
        const unsigned short* wp = wcat + (K_ << 6);                           \
        _Pragma("unroll")                                                      \
        for (int j = 0; j < 2; ++j) {                                          \
            int q = tid + 256 * j;                                             \
            RB[j] = *(const u16x8*)(wp + (size_t)(n0 + (q >> 3)) * 1152        \
                                       + ((q & 7) << 3));                      \
        }                                                                      \
    } while (0)

#define WRITE1(RA, RB, BUF) do {                                               \
        char* A_ = (BUF); char* B_ = (BUF) + 8192;                             \
        _Pragma("unroll")                                                      \
        for (int j = 0; j < 4; ++j) {                                          \
            int q = tid + 256 * j;                                             \
            u16x4 h;                                                           \
            h[0] = f2bf(RA[j][0]); h[1] = f2bf(RA[j][1]);                      \
            h[2] = f2bf(RA[j][2]); h[3] = f2bf(RA[j][3]);                      \
            *(u16x4*)(A_ + swz(q >> 4, (q & 15) << 3)) = h;                    \
        }                                                                      \
        _Pragma("unroll")                                                      \
        for (int j = 0; j < 2; ++j) {                                          \
            int q = tid + 256 * j;                                             \
            *(u16x8*)(B_ + swz(q >> 3, (q & 7) << 4)) = RB[j];                 \
        }                                                                      \
    } while (0)

#define COMPUTE1(BUF) do {                                                     \
        const char* A_ = (BUF); const char* B_ = (BUF) + 8192;                 \
        _Pragma("unroll")                                                      \
        for (int ks = 0; ks < 2; ++ks) {                                       \
            int kb = ks * 64 + lk2;                                            \
            bf16x8 af[2], bfr[2];                                              \
            _Pragma("unroll")                                                  \
            for (int mi = 0; mi < 2; ++mi)                                     \
                af[mi] = *(const bf16x8*)(A_ + swz(wm + mi * 16 + lrow, kb));  \
            _Pragma("unroll")                                                  \
            for (int nj = 0; nj < 2; ++nj)                                     \
                bfr[nj] = *(const bf16x8*)(B_ + swz(wn + nj * 16 + lrow, kb)); \
            _Pragma("unroll")                                                  \
            for (int mi = 0; mi < 2; ++mi)                                     \
                _Pragma("unroll")                                              \
                for (int nj = 0; nj < 2; ++nj)                                 \
                    acc[mi][nj] = __builtin_amdgcn_mfma_f32_16x16x32_bf16(     \
                        af[mi], bfr[nj], acc[mi][nj], 0, 0, 0);                \
        }                                                                      \
    } while (0)

    ISSUE1(ra0, rb0, 0);
    ISSUE1(ra1, rb1, 1);
    WRITE1(ra0, rb0, lds[0]);
    __syncthreads();

    #pragma unroll 1
    for (int i = 0; i < 9; ++i) {
        int kt = 2 * i;
        if (kt + 2 < 18) ISSUE1(ra0, rb0, kt + 2);
        COMPUTE1(lds[0]);
        WRITE1(ra1, rb1, lds[1]);
        __syncthreads();
        if (kt + 3 < 18) ISSUE1(ra1, rb1, kt + 3);
        COMPUTE1(lds[1]);
        if (kt + 2 < 18) WRITE1(ra0, rb0, lds[0]);
        __syncthreads();
    }

    // epilogue: bias + tanh (leaky term already folded into wcat)
    #pragma unroll
    for (int nj = 0; nj < 2; ++nj) {
        int gn = n0 + wn + nj * 16 + lrow;
        float bb = 0.5f * (b1[gn] + b2[gn] + b3[gn]);
        #pragma unroll
        for (int mi = 0; mi < 2; ++mi) {
            #pragma unroll
            for (int r = 0; r < 4; ++r) {
                int gm = m0 + wm + mi * 16 + ((lane >> 4) << 2) + r;
                ionew[(size_t)gm * 512 + gn] = f2bf(tanhf(acc[mi][nj][r] + bb));
            }
        }
    }
#undef ISSUE1
#undef WRITE1
#undef COMPUTE1
}

// ---------------------------------------------------------------------------
// Kernel 2: y = tanh(ionew @ w2^T + bio2o). M=8192 N=128 K=512.
// Tile 32x64, BK=64, 128 thr (2 waves, wave 16x64). Grid 512 -> 2 blocks/CU.
// 2-deep issue pipeline. XCD map matches gemm1's ionew writer XCD.
// ---------------------------------------------------------------------------
__global__ __launch_bounds__(128, 2) void k_gemm2(
    const unsigned short* __restrict__ ionew,
    const unsigned short* __restrict__ w2,
    const float* __restrict__ b_io2o,
    float* __restrict__ out)
{
    // per buffer: A 32x64 (4 KB) @0, B 64x64 (8 KB) @4096
    __shared__ __align__(16) char lds[2][12288];

    const int tid = threadIdx.x;
    const int b   = blockIdx.x;
    // ionew rows [1024x, 1024(x+1)) were produced on XCD x; read them there.
    const int xcd = b & 7;
    const int j8  = b >> 3;                    // 0..63
    const int r2  = (xcd << 5) | (j8 & 31);    // 0..255
    const int c2  = j8 >> 5;                   // 0..1
    const int m0 = r2 << 5;
    const int n0 = c2 << 6;

    const int lane = tid & 63;
    const int wid  = tid >> 6;        // 0..1
    const int wm   = wid << 4;        // 0 / 16
    const int lrow = lane & 15;
    const int lk2  = (lane >> 4) << 4;

    u16x8 ra0[2], rb0[4], ra1[2], rb1[4];
    f32x4 acc[4];
    f32x4 z = {0.f, 0.f, 0.f, 0.f};
    #pragma unroll
    for (int j = 0; j < 4; ++j) acc[j] = z;

#define ISSUE2(RA, RB, KT) do {                                                \
        const unsigned short* ap = ionew + ((KT) << 6);                        \
        _Pragma("unroll")                                                      \
        for (int j = 0; j < 2; ++j) {                                          \
            int q = tid + 128 * j;                                             \
            RA[j] = *(const u16x8*)(ap + (size_t)(m0 + (q >> 3)) * 512         \
                                       + ((q & 7) << 3));                      \
        }                                                                      \
        const unsigned short* bp = w2 + ((KT) << 6);                           \
        _Pragma("unroll")                                                      \
        for (int j = 0; j < 4; ++j) {                                          \
            int q = tid + 128 * j;                                             \
            RB[j] = *(const u16x8*)(bp + (size_t)(n0 + (q >> 3)) * 512         \
                                       + ((q & 7) << 3));                      \
        }                                                                      \
    } while (0)

#define WRITE2(RA, RB, BUF) do {                                               \
        char* A_ = (BUF); char* B_ = (BUF) + 4096;                             \
        _Pragma("unroll")                                                      \
        for (int j = 0; j < 2; ++j) {                                          \
            int q = tid + 128 * j;                                             \
            *(u16x8*)(A_ + swz(q >> 3, (q & 7) << 4)) = RA[j];                 \
        }                                                                      \
        _Pragma("unroll")                                                      \
        for (int j = 0; j < 4; ++j) {                                          \
            int q = tid + 128 * j;                                             \
            *(u16x8*)(B_ + swz(q >> 3, (q & 7) << 4)) = RB[j];                 \
        }                                                                      \
    } while (0)

#define COMPUTE2(BUF) do {                                                     \
        const char* A_ = (BUF); const char* B_ = (BUF) + 4096;                 \
        _Pragma("unroll")                                                      \
        for (int ks = 0; ks < 2; ++ks) {                                       \
            int kb = ks * 64 + lk2;                                            \
            bf16x8 af = *(const bf16x8*)(A_ + swz(wm + lrow, kb));             \
            _Pragma("unroll")                                                  \
            for (int nj = 0; nj < 4; ++nj) {                                   \
                bf16x8 bfr = *(const bf16x8*)(B_ + swz(nj * 16 + lrow, kb));   \
                acc[nj] = __builtin_amdgcn_mfma_f32_16x16x32_bf16(             \
                    af, bfr, acc[nj], 0, 0, 0);                                \
            }                                                                  \
        }                                                                      \
    } while (0)

    ISSUE2(ra0, rb0, 0);
    ISSUE2(ra1, rb1, 1);
    WRITE2(ra0, rb0, lds[0]);
    __syncthreads();

    #pragma unroll 1
    for (int i = 0; i < 4; ++i) {
        int kt = 2 * i;
        if (kt + 2 < 8) ISSUE2(ra0, rb0, kt + 2);
        COMPUTE2(lds[0]);
        WRITE2(ra1, rb1, lds[1]);
        __syncthreads();
        if (kt + 3 < 8) ISSUE2(ra1, rb1, kt + 3);
        COMPUTE2(lds[1]);
        if (kt + 2 < 8) WRITE2(ra0, rb0, lds[0]);
        __syncthreads();
    }

    #pragma unroll
    for (int nj = 0; nj < 4; ++nj) {
        int col  = n0 + nj * 16 + lrow;
        float bb = b_io2o[col];
        #pragma unroll
        for (int r = 0; r < 4; ++r) {
            int gm = m0 + wm + ((lane >> 4) << 2) + r;
            out[(size_t)gm * 128 + col] = tanhf(acc[nj][r] + bb);
        }
    }
#undef ISSUE2
#undef WRITE2
#undef COMPUTE2
}

// ---------------------------------------------------------------------------
extern "C" void kernel_launch(void* const* d_in, const int* in_sizes, int n_in,
                              void* d_out, int out_size, void* d_ws, size_t ws_size,
                              hipStream_t stream)
{
    const float* x      = (const float*)d_in[0];
    const float* io     = (const float*)d_in[1];
    const float* cf     = (const float*)d_in[2];
    // d_in[3] cs_state: dead (does not feed y)
    const float* Wi2io  = (const float*)d_in[4];
    const float* bi2io  = (const float*)d_in[5];
    const float* Wio2o  = (const float*)d_in[6];
    const float* bio2o  = (const float*)d_in[7];
    const float* Wio2io = (const float*)d_in[8];
    const float* bio2io = (const float*)d_in[9];
    const float* Wcf2io = (const float*)d_in[12];
    const float* bcf2io = (const float*)d_in[13];
    float* out = (float*)d_out;

    // workspace layout (bytes): wcat 1,179,648 | w2 131,072 | ionew 8,388,608
    char* ws = (char*)d_ws;
    unsigned short* wcat  = (unsigned short*)ws;
    unsigned short* w2    = (unsigned short*)(ws + 1179648);
    unsigned short* ionew = (unsigned short*)(ws + 1310720);

    hipLaunchKernelGGL(k_convert, dim3(640), dim3(256), 0, stream,
                       Wi2io, Wio2io, Wcf2io, Wio2o, wcat, w2);
    hipLaunchKernelGGL(k_gemm1, dim3(1024), dim3(256), 0, stream,
                       x, io, cf, wcat, bi2io, bio2io, bcf2io, ionew);
    hipLaunchKernelGGL(k_gemm2, dim3(512), dim3(128), 0, stream,
                       ionew, w2, bio2o, out);
}

// Round 4
// 38.977 us; speedup vs baseline: 1.0624x; 1.0624x over previous
//
#include <hip/hip_runtime.h>

// MTRNN single step. Live computation after DCE (reference returns only y):
//   io_new = tanh([x|io|cf] @ (0.5*[Wi2io | Wio2io+I | Wcf2io])^T + 0.5*bsum)
//   y      = tanh(io_new @ Wio2o^T + bio2o)
// (0.5*io_state folded into the weight matrix via +I on the io2io block.)
// cf_new / cs_new are dead code. bf16 MFMA, f32 accumulate.

typedef float f32x4 __attribute__((ext_vector_type(4)));
typedef __bf16 bf16x4 __attribute__((ext_vector_type(4)));
typedef __bf16 bf16x8 __attribute__((ext_vector_type(8)));
typedef unsigned short u16x8 __attribute__((ext_vector_type(8)));
typedef unsigned short u16x4 __attribute__((ext_vector_type(4)));

__device__ __forceinline__ unsigned short f2bf(float f) {
    unsigned u = __builtin_bit_cast(unsigned, f);
    u += 0x7FFFu + ((u >> 16) & 1u);
    return (unsigned short)(u >> 16);
}

// XOR swizzle for [rows][64] bf16 tiles (row stride 128 B).
__device__ __forceinline__ int swz(int row, int kbyte) {
    return ((row << 7) + kbyte) ^ ((row & 7) << 4);
}

// Raw workgroup barrier WITHOUT the vmcnt(0) drain __syncthreads carries.
// lgkmcnt(0) makes this wave's ds_writes visible; global loads in flight
// (VGPR dests) stay in flight — the compiler waits on them only at use.
__device__ __forceinline__ void barrier_lds() {
    asm volatile("s_waitcnt lgkmcnt(0)\n\ts_barrier" ::: "memory");
}

// ---------------------------------------------------------------------------
// Kernel 0: pack live weights to bf16.
//   wcat[512][1152] = 0.5*[Wi2io | Wio2io + I | Wcf2io]   (leaky-int folded)
//   w2  [128][512]  = Wio2o
// ---------------------------------------------------------------------------
__global__ __launch_bounds__(256) void k_convert(
    const float* __restrict__ Wi2io, const float* __restrict__ Wio2io,
    const float* __restrict__ Wcf2io, const float* __restrict__ Wio2o,
    unsigned short* __restrict__ wcat, unsigned short* __restrict__ w2)
{
    int idx = blockIdx.x * 256 + threadIdx.x;
    if (idx < 147456) {              // 512*1152/4 quads
        int n = idx / 288;
        int k = (idx - n * 288) * 4;
        const float* s;
        if (k < 128)      s = Wi2io  + n * 128 + k;
        else if (k < 640) s = Wio2io + n * 512 + (k - 128);
        else              s = Wcf2io + n * 512 + (k - 640);
        f32x4 v = *(const f32x4*)s;
        u16x4 h;
        #pragma unroll
        for (int t = 0; t < 4; ++t) {
            float f = 0.5f * v[t];
            int kk = k + t;
            if (kk >= 128 && kk < 640 && (kk - 128) == n) f += 0.5f;  // +0.5*I
            h[t] = f2bf(f);
        }
        *(u16x4*)(wcat + n * 1152 + k) = h;
    } else if (idx < 163840) {       // + 128*512/4 quads
        int q = idx - 147456;
        int n = q >> 7;
        int k = (q & 127) * 4;
        f32x4 v = *(const f32x4*)(Wio2o + n * 512 + k);
        u16x4 h; h[0]=f2bf(v[0]); h[1]=f2bf(v[1]); h[2]=f2bf(v[2]); h[3]=f2bf(v[3]);
        *(u16x4*)(w2 + n * 512 + k) = h;
    }
}

// ---------------------------------------------------------------------------
// Kernel 1: ionew = tanh(Acat @ wcat^T + 0.5*bsum), bf16 out.
// M=8192 N=512 K=1152. Tile 128x128, BK=64, 512 thr (8 waves 2x4, wave
// 64x32). Grid 256 (1 block/CU). Double-buffered LDS, 2-deep issue, raw
// barriers (loads stay in flight across barriers -> true pipeline).
// ---------------------------------------------------------------------------
__global__ __launch_bounds__(512, 2) void k_gemm1(
    const float* __restrict__ x, const float* __restrict__ io,
    const float* __restrict__ cf,
    const unsigned short* __restrict__ wcat,
    const float* __restrict__ b1, const float* __restrict__ b2,
    const float* __restrict__ b3,
    unsigned short* __restrict__ ionew)
{
    // per buffer: A 128x64 bf16 (16 KB) @0, B 128x64 bf16 (16 KB) @16384
    __shared__ __align__(16) char lds[2][32768];

    const int tid = threadIdx.x;
    const int b   = blockIdx.x;
    // XCD x (= b&7) owns A panels [8x, 8x+8), all 4 col-blocks.
    const int xcd = b & 7;
    const int idx = b >> 3;                    // 0..31
    const int m0  = (((xcd << 3) | (idx & 7))) << 7;
    const int n0  = (idx >> 3) << 7;

    const int lane = tid & 63;
    const int wid  = tid >> 6;
    const int wm   = (wid >> 2) << 6;     // 0 / 64
    const int wn   = (wid & 3) << 5;      // 0 / 32 / 64 / 96
    const int lrow = lane & 15;
    const int lk2  = (lane >> 4) << 4;    // k byte offset within 128B row

    // A staging map: q = tid + 512j -> row = (tid>>4) + 32j, quad = tid&15
    const int arow = tid >> 4, aq = tid & 15;
    const size_t aoff_x = (size_t)(m0 + arow) * 128 + aq * 4;
    const size_t aoff_s = (size_t)(m0 + arow) * 512 + aq * 4;
    const int law = swz(arow, aq * 8);        // +j*4096 for rows +32j
    // B staging map: q = tid + 512j -> row = (tid>>3) + 64j, gran = tid&7
    const size_t boff = (size_t)(n0 + (tid >> 3)) * 1152 + (tid & 7) * 8;
    const int lbw = swz(tid >> 3, (tid & 7) * 16);   // +j*8192 for rows +64j

    f32x4 qa0, qa1, qa2, qa3, pa0, pa1, pa2, pa3;
    u16x8 qb0, qb1, pb0, pb1;
    f32x4 acc[4][2];
    f32x4 z = {0.f, 0.f, 0.f, 0.f};
    #pragma unroll
    for (int i = 0; i < 4; ++i)
        #pragma unroll
        for (int j = 0; j < 2; ++j) acc[i][j] = z;

#define ISSUE1(A0, A1, A2, A3, B0, B1, KT) do {                                \
        int K_ = (KT);                                                         \
        const float* ap; size_t step;                                          \
        if (K_ < 2)       { ap = x  + aoff_x + (size_t)(K_) * 64;              \
                            step = (size_t)32 * 128; }                         \
        else if (K_ < 10) { ap = io + aoff_s + (size_t)(K_ - 2) * 64;          \
                            step = (size_t)32 * 512; }                         \
        else              { ap = cf + aoff_s + (size_t)(K_ - 10) * 64;         \
                            step = (size_t)32 * 512; }                         \
        A0 = *(const f32x4*)(ap);                                              \
        A1 = *(const f32x4*)(ap + step);                                       \
        A2 = *(const f32x4*)(ap + 2 * step);                                   \
        A3 = *(const f32x4*)(ap + 3 * step);                                   \
        const unsigned short* bp = wcat + boff + (size_t)(K_) * 64;            \
        B0 = *(const u16x8*)(bp);                                              \
        B1 = *(const u16x8*)(bp + (size_t)64 * 1152);                          \
    } while (0)

#define WRITE1(A0, A1, A2, A3, B0, B1, BUF) do {                               \
        char* A_ = (BUF); char* B_ = (BUF) + 16384;                            \
        *(bf16x4*)(A_ + law)         = __builtin_convertvector(A0, bf16x4);    \
        *(bf16x4*)(A_ + law + 4096)  = __builtin_convertvector(A1, bf16x4);    \
        *(bf16x4*)(A_ + law + 8192)  = __builtin_convertvector(A2, bf16x4);    \
        *(bf16x4*)(A_ + law + 12288) = __builtin_convertvector(A3, bf16x4);    \
        *(u16x8*)(B_ + lbw)          = B0;                                     \
        *(u16x8*)(B_ + lbw + 8192)   = B1;                                     \
    } while (0)

#define COMPUTE1(BUF) do {                                                     \
        const char* A_ = (BUF); const char* B_ = (BUF) + 16384;                \
        _Pragma("unroll")                                                      \
        for (int ks = 0; ks < 2; ++ks) {                                       \
            int kb = ks * 64 + lk2;                                            \
            bf16x8 af[4]; bf16x8 bfr[2];                                       \
            _Pragma("unroll")                                                  \
            for (int mi = 0; mi < 4; ++mi)                                     \
                af[mi] = *(const bf16x8*)(A_ + swz(wm + mi * 16 + lrow, kb));  \
            _Pragma("unroll")                                                  \
            for (int nj = 0; nj < 2; ++nj)                                     \
                bfr[nj] = *(const bf16x8*)(B_ + swz(wn + nj * 16 + lrow, kb)); \
            _Pragma("unroll")                                                  \
            for (int mi = 0; mi < 4; ++mi)                                     \
                _Pragma("unroll")                                              \
                for (int nj = 0; nj < 2; ++nj)                                 \
                    acc[mi][nj] = __builtin_amdgcn_mfma_f32_16x16x32_bf16(     \
                        af[mi], bfr[nj], acc[mi][nj], 0, 0, 0);                \
        }                                                                      \
    } while (0)

    ISSUE1(qa0, qa1, qa2, qa3, qb0, qb1, 0);
    ISSUE1(pa0, pa1, pa2, pa3, pb0, pb1, 1);
    WRITE1(qa0, qa1, qa2, qa3, qb0, qb1, lds[0]);
    barrier_lds();

    #pragma unroll 1
    for (int i = 0; i < 9; ++i) {
        int kt = 2 * i;
        if (kt + 2 < 18) ISSUE1(qa0, qa1, qa2, qa3, qb0, qb1, kt + 2);
        COMPUTE1(lds[0]);
        WRITE1(pa0, pa1, pa2, pa3, pb0, pb1, lds[1]);
        barrier_lds();
        if (kt + 3 < 18) ISSUE1(pa0, pa1, pa2, pa3, pb0, pb1, kt + 3);
        COMPUTE1(lds[1]);
        if (kt + 2 < 18) WRITE1(qa0, qa1, qa2, qa3, qb0, qb1, lds[0]);
        barrier_lds();
    }

    // epilogue: bias + tanh (leaky term already folded into wcat)
    #pragma unroll
    for (int nj = 0; nj < 2; ++nj) {
        int gn = n0 + wn + nj * 16 + lrow;
        float bb = 0.5f * (b1[gn] + b2[gn] + b3[gn]);
        #pragma unroll
        for (int mi = 0; mi < 4; ++mi) {
            #pragma unroll
            for (int r = 0; r < 4; ++r) {
                int gm = m0 + wm + mi * 16 + ((lane >> 4) << 2) + r;
                ionew[(size_t)gm * 512 + gn] = f2bf(tanhf(acc[mi][nj][r] + bb));
            }
        }
    }
#undef ISSUE1
#undef WRITE1
#undef COMPUTE1
}

// ---------------------------------------------------------------------------
// Kernel 2: y = tanh(ionew @ w2^T + bio2o). M=8192 N=128 K=512.
// Tile 32x128 (full N), BK=64, 256 thr (4 waves 2x2, wave 16x64). Grid 256.
// Same raw-barrier 2-deep pipeline. XCD map matches gemm1's ionew writers.
// ---------------------------------------------------------------------------
__global__ __launch_bounds__(256, 2) void k_gemm2(
    const unsigned short* __restrict__ ionew,
    const unsigned short* __restrict__ w2,
    const float* __restrict__ b_io2o,
    float* __restrict__ out)
{
    // per buffer: A 32x64 (4 KB) @0, B 128x64 (16 KB) @4096
    __shared__ __align__(16) char lds[2][20480];

    const int tid = threadIdx.x;
    const int b   = blockIdx.x;
    // rows [1024x, 1024(x+1)) were produced on XCD x; consume them there.
    const int xcd = b & 7;
    const int idx = b >> 3;                     // 0..31
    const int m0  = ((xcd << 5) | idx) << 5;

    const int lane = tid & 63;
    const int wid  = tid >> 6;
    const int wm   = (wid >> 1) << 4;     // 0 / 16
    const int wn   = (wid & 1) << 6;      // 0 / 64
    const int lrow = lane & 15;
    const int lk2  = (lane >> 4) << 4;

    // A: row = tid>>3 (0..31), gran = tid&7
    const size_t aoff = (size_t)(m0 + (tid >> 3)) * 512 + (tid & 7) * 8;
    const int law = swz(tid >> 3, (tid & 7) * 16);
    // B: q = tid + 256j -> row = (tid>>3) + 32j
    const size_t boff = (size_t)(tid >> 3) * 512 + (tid & 7) * 8;
    const int lbw = swz(tid >> 3, (tid & 7) * 16);   // +j*4096 for +32 rows

    u16x8 qa, qb0, qb1, qb2, qb3, pa, pb0, pb1, pb2, pb3;
    f32x4 acc[4];
    f32x4 z = {0.f, 0.f, 0.f, 0.f};
    #pragma unroll
    for (int j = 0; j < 4; ++j) acc[j] = z;

#define ISSUE2(A0, B0, B1, B2, B3, KT) do {                                    \
        const unsigned short* ap = ionew + aoff + (size_t)(KT) * 64;           \
        A0 = *(const u16x8*)(ap);                                              \
        const unsigned short* bp = w2 + boff + (size_t)(KT) * 64;              \
        B0 = *(const u16x8*)(bp);                                              \
        B1 = *(const u16x8*)(bp + (size_t)32 * 512);                           \
        B2 = *(const u16x8*)(bp + (size_t)64 * 512);                           \
        B3 = *(const u16x8*)(bp + (size_t)96 * 512);                           \
    } while (0)

#define WRITE2(A0, B0, B1, B2, B3, BUF) do {                                   \
        char* A_ = (BUF); char* B_ = (BUF) + 4096;                             \
        *(u16x8*)(A_ + law)         = A0;                                      \
        *(u16x8*)(B_ + lbw)         = B0;                                      \
        *(u16x8*)(B_ + lbw + 4096)  = B1;                                      \
        *(u16x8*)(B_ + lbw + 8192)  = B2;                                      \
        *(u16x8*)(B_ + lbw + 12288) = B3;                                      \
    } while (0)

#define COMPUTE2(BUF) do {                                                     \
        const char* A_ = (BUF); const char* B_ = (BUF) + 4096;                 \
        _Pragma("unroll")                                                      \
        for (int ks = 0; ks < 2; ++ks) {                                       \
            int kb = ks * 64 + lk2;                                            \
            bf16x8 af = *(const bf16x8*)(A_ + swz(wm + lrow, kb));             \
            _Pragma("unroll")                                                  \
            for (int nj = 0; nj < 4; ++nj) {                                   \
                bf16x8 bfr = *(const bf16x8*)(B_ + swz(wn + nj * 16 + lrow, kb)); \
                acc[nj] = __builtin_amdgcn_mfma_f32_16x16x32_bf16(             \
                    af, bfr, acc[nj], 0, 0, 0);                                \
            }                                                                  \
        }                                                                      \
    } while (0)

    ISSUE2(qa, qb0, qb1, qb2, qb3, 0);
    ISSUE2(pa, pb0, pb1, pb2, pb3, 1);
    WRITE2(qa, qb0, qb1, qb2, qb3, lds[0]);
    barrier_lds();

    #pragma unroll 1
    for (int i = 0; i < 4; ++i) {
        int kt = 2 * i;
        if (kt + 2 < 8) ISSUE2(qa, qb0, qb1, qb2, qb3, kt + 2);
        COMPUTE2(lds[0]);
        WRITE2(pa, pb0, pb1, pb2, pb3, lds[1]);
        barrier_lds();
        if (kt + 3 < 8) ISSUE2(pa, pb0, pb1, pb2, pb3, kt + 3);
        COMPUTE2(lds[1]);
        if (kt + 2 < 8) WRITE2(qa, qb0, qb1, qb2, qb3, lds[0]);
        barrier_lds();
    }

    #pragma unroll
    for (int nj = 0; nj < 4; ++nj) {
        int col  = wn + nj * 16 + lrow;
        float bb = b_io2o[col];
        #pragma unroll
        for (int r = 0; r < 4; ++r) {
            int gm = m0 + wm + ((lane >> 4) << 2) + r;
            out[(size_t)gm * 128 + col] = tanhf(acc[nj][r] + bb);
        }
    }
#undef ISSUE2
#undef WRITE2
#undef COMPUTE2
}

// ---------------------------------------------------------------------------
extern "C" void kernel_launch(void* const* d_in, const int* in_sizes, int n_in,
                              void* d_out, int out_size, void* d_ws, size_t ws_size,
                              hipStream_t stream)
{
    const float* x      = (const float*)d_in[0];
    const float* io     = (const float*)d_in[1];
    const float* cf     = (const float*)d_in[2];
    // d_in[3] cs_state: dead (does not feed y)
    const float* Wi2io  = (const float*)d_in[4];
    const float* bi2io  = (const float*)d_in[5];
    const float* Wio2o  = (const float*)d_in[6];
    const float* bio2o  = (const float*)d_in[7];
    const float* Wio2io = (const float*)d_in[8];
    const float* bio2io = (const float*)d_in[9];
    const float* Wcf2io = (const float*)d_in[12];
    const float* bcf2io = (const float*)d_in[13];
    float* out = (float*)d_out;

    // workspace layout (bytes): wcat 1,179,648 | w2 131,072 | ionew 8,388,608
    char* ws = (char*)d_ws;
    unsigned short* wcat  = (unsigned short*)ws;
    unsigned short* w2    = (unsigned short*)(ws + 1179648);
    unsigned short* ionew = (unsigned short*)(ws + 1310720);

    hipLaunchKernelGGL(k_convert, dim3(640), dim3(256), 0, stream,
                       Wi2io, Wio2io, Wcf2io, Wio2o, wcat, w2);
    hipLaunchKernelGGL(k_gemm1, dim3(256), dim3(512), 0, stream,
                       x, io, cf, wcat, bi2io, bio2io, bcf2io, ionew);
    hipLaunchKernelGGL(k_gemm2, dim3(256), dim3(256), 0, stream,
                       ionew, w2, bio2o, out);
}